// Round 4
// baseline (4469.666 us; speedup 1.0000x reference)
//
#include <hip/hip_runtime.h>
#include <hip/hip_bf16.h>
#include <math.h>

// Problem constants (MiniTrajectoryPredictor)
#define BB 32
#define TT 24
#define OO 128
#define HH 512
#define CTXD 256
#define HOR 48
#define NN (BB*OO)        // 4096
#define G3 (3*HH)         // 1536
#define KS 17             // k-steps of 32 (512 h + [x0,x1,1] + pad)

typedef unsigned short ushortt;
typedef __attribute__((ext_vector_type(8))) short bf16x8;
typedef __attribute__((ext_vector_type(4))) float f32x4;

// ---- bf16 split helpers ----
__device__ __forceinline__ ushortt f2bf(float x) {
    union { float f; unsigned u; } v; v.f = x;
    unsigned r = v.u + 0x7FFF + ((v.u >> 16) & 1);
    return (ushortt)(r >> 16);
}
__device__ __forceinline__ float bf2f(ushortt b) {
    union { unsigned u; float f; } v; v.u = ((unsigned)b) << 16;
    return v.f;
}
__device__ __forceinline__ void splitbf(float x, ushortt& hi, ushortt& lo) {
    hi = f2bf(x);
    lo = f2bf(x - bf2f(hi));
}
__device__ __forceinline__ float sigm(float x) { return 1.f / (1.f + __expf(-x)); }
__device__ __forceinline__ float tanh_fast(float x) {
    float xc = fminf(fmaxf(x, -10.f), 10.f);
    float e = __expf(2.f * xc);
    return (e - 1.f) / (e + 1.f);
}

// Fragment layout (verified R2/R3): element (row r, k) of a 16-row tile lives at
// lane = ((k%32)>>3)*16 + (r%16), slot = k%8; buffer [tile][ks][lane][slot] u16.
// C/D: col = lane&15, row = (lane>>4)*4 + reg.

// ================= fused gh-GEMM + GRU step =================
// Wave tile: 64 rows (4 m-tiles) x 96 cols (3 gates x 32 j = 6 n-tiles) -> 28.8 MAC/B intensity.
// Block: 4 row-stacked waves = 256 rows x 32 j-cols. Grid 16 x 16 = 256 (1 block/CU, 1 wave/SIMD).

#define STEP_LOADA(Ad, ksv) do { const size_t ko = (size_t)(ksv) * 512; \
  _Pragma("unroll") for (int m_ = 0; m_ < 4; m_++) { \
    Ad[m_*2+0] = *reinterpret_cast<const bf16x8*>(RAh + ao[m_] + ko); \
    Ad[m_*2+1] = *reinterpret_cast<const bf16x8*>(RAl + ao[m_] + ko); \
  } } while(0)
#define STEP_LOADB(Bd, ksv) do { const size_t ko = (size_t)(ksv) * 512; \
  _Pragma("unroll") for (int i_ = 0; i_ < 6; i_++) { \
    Bd[i_*2+0] = *reinterpret_cast<const bf16x8*>(Bh + bo[i_] + ko); \
    Bd[i_*2+1] = *reinterpret_cast<const bf16x8*>(Bl + bo[i_] + ko); \
  } } while(0)
#define STEP_MFMA(Av, Bv) do { \
  _Pragma("unroll") for (int m_ = 0; m_ < 4; m_++) \
  _Pragma("unroll") for (int i_ = 0; i_ < 6; i_++) \
    acc[m_][i_] = __builtin_amdgcn_mfma_f32_16x16x32_bf16(Av[m_*2+0], Bv[i_*2+0], acc[m_][i_], 0,0,0); \
  _Pragma("unroll") for (int m_ = 0; m_ < 4; m_++) \
  _Pragma("unroll") for (int i_ = 0; i_ < 6; i_++) \
    acc[m_][i_] = __builtin_amdgcn_mfma_f32_16x16x32_bf16(Av[m_*2+0], Bv[i_*2+1], acc[m_][i_], 0,0,0); \
  _Pragma("unroll") for (int m_ = 0; m_ < 4; m_++) \
  _Pragma("unroll") for (int i_ = 0; i_ < 6; i_++) \
    acc[m_][i_] = __builtin_amdgcn_mfma_f32_16x16x32_bf16(Av[m_*2+1], Bv[i_*2+0], acc[m_][i_], 0,0,0); \
  } while(0)

template<bool ENC>
__global__ __launch_bounds__(256, 1) void step_kernel(
    const ushortt* __restrict__ RAh, const ushortt* __restrict__ RAl,   // read h frags
    ushortt* __restrict__ WAh, ushortt* __restrict__ WAl,               // write h frags
    const ushortt* __restrict__ Bh, const ushortt* __restrict__ Bl,     // Wh_ext frags
    const float* __restrict__ U, const float* __restrict__ cin,
    const float* __restrict__ xsrc, int t, const float* __restrict__ ctx)
{
    __shared__ float hbuf[256 * 36];   // 36.9 KB; stride 36 keeps float4 alignment, 2-way banks (free)
    const int mb = blockIdx.x >> 4;    // 0..15  (256 rows each)
    const int jb = blockIdx.x & 15;    // 0..15  (32 j-cols per gate)
    const int w = threadIdx.x >> 6, lane = threadIdx.x & 63;
    const int quad = lane >> 4, l15 = lane & 15;
    const int mtg = mb * 16 + w * 4;   // wave's 4 global m-tiles

    f32x4 acc[4][6];
#pragma unroll
    for (int a = 0; a < 4; a++)
#pragma unroll
        for (int b = 0; b < 6; b++) acc[a][b] = (f32x4){0.f,0.f,0.f,0.f};

    size_t ao[4];
    unsigned bo[6];
#pragma unroll
    for (int mt = 0; mt < 4; mt++) ao[mt] = (size_t)(mtg + mt) * (KS*512) + lane * 8;
#pragma unroll
    for (int g = 0; g < 3; g++)
#pragma unroll
        for (int jt = 0; jt < 2; jt++)
            bo[g*2+jt] = (unsigned)(g*32 + jb*2 + jt) * (KS*512) + lane * 8;

    bf16x8 aC[8], bC[12], aN[8], bN[12];
    STEP_LOADA(aC, 0); STEP_LOADB(bC, 0);
#pragma unroll 1
    for (int ks = 0; ks < 16; ks += 2) {
        STEP_LOADA(aN, ks+1); STEP_LOADB(bN, ks+1);
        STEP_MFMA(aC, bC);
        STEP_LOADA(aC, ks+2); STEP_LOADB(bC, ks+2);
        STEP_MFMA(aN, bN);
    }
    STEP_MFMA(aC, bC);

    // ---------------- GRU epilogue ----------------
    const int jlo = jb * 32;
    float u0[2], u1[2], cc[2];
#pragma unroll
    for (int jt = 0; jt < 2; jt++) {
        int j = jlo + jt*16 + l15;
        u0[jt] = U[(1024 + j) * 2];
        u1[jt] = U[(1024 + j) * 2 + 1];
        cc[jt] = cin[1024 + j];
    }
    float x0v[4][4], x1v[4][4];
#pragma unroll
    for (int mt = 0; mt < 4; mt++)
#pragma unroll
        for (int reg = 0; reg < 4; reg++) {
            int row = (mtg + mt) * 16 + quad * 4 + reg;
            const float* p;
            if (ENC) p = xsrc + (((size_t)(row >> 7) * TT + t) * OO + (row & 127)) * 2;
            else     p = xsrc + (size_t)row * 2;
            x0v[mt][reg] = p[0]; x1v[mt][reg] = p[1];
        }
#pragma unroll
    for (int mt = 0; mt < 4; mt++)
#pragma unroll
        for (int jt = 0; jt < 2; jt++) {
            int qk = jt*2 + (l15 >> 3), slot = l15 & 7;
#pragma unroll
            for (int reg = 0; reg < 4; reg++) {
                int row = (mtg + mt) * 16 + quad * 4 + reg;
                float pr = acc[mt][0*2+jt][reg];
                float pz = acc[mt][1*2+jt][reg];
                float hn = acc[mt][2*2+jt][reg];
                size_t pos = (((size_t)(mtg + mt) * KS + jb) * 64 + qk*16 + quad*4 + reg) * 8 + slot;
                float hold = bf2f(RAh[pos]) + bf2f(RAl[pos]);
                float inn = fmaf(x1v[mt][reg], u1[jt], fmaf(x0v[mt][reg], u0[jt], cc[jt]));
                float rg = sigm(pr), zg = sigm(pz);
                float nn = tanh_fast(inn + rg * hn);
                float h = (1.f - zg) * nn + zg * hold;
                if (ENC && t == TT - 1) h += ctx[(size_t)(row >> 7) * HH + jlo + jt*16 + l15];
                hbuf[(w*64 + mt*16 + quad*4 + reg) * 36 + jt*16 + l15] = h;
            }
        }
    __syncthreads();
    // repack LDS tile (256 rows x 32 j) -> A-frags ks == jb of write buffer: 16 tiles x 64 frag-lanes
#pragma unroll
    for (int rr = 0; rr < 4; rr++) {
        int fr = threadIdx.x + 256 * rr;       // 0..1023
        int mt16 = fr >> 6, fl = fr & 63;
        int qk = fl >> 4, rloc = mt16 * 16 + (fl & 15);
        const float4 v0 = *reinterpret_cast<const float4*>(&hbuf[rloc * 36 + qk * 8]);
        const float4 v1 = *reinterpret_cast<const float4*>(&hbuf[rloc * 36 + qk * 8 + 4]);
        float src[8] = {v0.x, v0.y, v0.z, v0.w, v1.x, v1.y, v1.z, v1.w};
        bf16x8 hv, lv;
#pragma unroll
        for (int s = 0; s < 8; s++) {
            ushortt hi, lo; splitbf(src[s], hi, lo);
            hv[s] = (short)hi; lv[s] = (short)lo;
        }
        size_t base = (((size_t)(mb*16 + mt16) * KS + jb) * 64 + fl) * 8;
        *reinterpret_cast<bf16x8*>(WAh + base) = hv;
        *reinterpret_cast<bf16x8*>(WAl + base) = lv;
    }
    // encoder write-ahead: next step's x into write buffer ks=16 (slots 0,1)
    if (ENC && jb == 0) {
        int row = mb * 256 + threadIdx.x;
        int tn = (t < TT - 1) ? (t + 1) : (TT - 1);
        const float* p = xsrc + (((size_t)(row >> 7) * TT + tn) * OO + (row & 127)) * 2;
        ushortt h0, l0, h1, l1;
        splitbf(p[0], h0, l0); splitbf(p[1], h1, l1);
        size_t xb = (((size_t)(row >> 4) * KS + 16) * 64 + (row & 15)) * 8;
        WAh[xb + 0] = h0; WAl[xb + 0] = l0;
        WAh[xb + 1] = h1; WAl[xb + 1] = l1;
    }
}

// ================= fused head: t1 = gelu(h@W1^T + b1); d += t1@W2^T; last block finalizes =================
// Wave 64 rows x 32 cols (4 mt x 2 nt). Block 256 rows x 32 cols. Grid 16 x 16 = 256.
#define HEAD_LOADA(Ad, ksv) do { const size_t ko = (size_t)(ksv) * 512; \
  _Pragma("unroll") for (int m_ = 0; m_ < 4; m_++) { \
    Ad[m_*2+0] = *reinterpret_cast<const bf16x8*>(Ah + hao[m_] + ko); \
    Ad[m_*2+1] = *reinterpret_cast<const bf16x8*>(Al + hao[m_] + ko); \
  } } while(0)
#define HEAD_LOADB(Bd, ksv) do { const size_t ko = (size_t)(ksv) * 512; \
  _Pragma("unroll") for (int n_ = 0; n_ < 2; n_++) { \
    Bd[n_*2+0] = *reinterpret_cast<const bf16x8*>(Bh + hbo[n_] + ko); \
    Bd[n_*2+1] = *reinterpret_cast<const bf16x8*>(Bl + hbo[n_] + ko); \
  } } while(0)
#define HEAD_MFMA(Av, Bv) do { \
  _Pragma("unroll") for (int m_ = 0; m_ < 4; m_++) \
  _Pragma("unroll") for (int n_ = 0; n_ < 2; n_++) { \
    acc[m_][n_] = __builtin_amdgcn_mfma_f32_16x16x32_bf16(Av[m_*2+0], Bv[n_*2+0], acc[m_][n_], 0,0,0); \
    acc[m_][n_] = __builtin_amdgcn_mfma_f32_16x16x32_bf16(Av[m_*2+0], Bv[n_*2+1], acc[m_][n_], 0,0,0); \
    acc[m_][n_] = __builtin_amdgcn_mfma_f32_16x16x32_bf16(Av[m_*2+1], Bv[n_*2+0], acc[m_][n_], 0,0,0); \
  } } while(0)

__global__ __launch_bounds__(256, 1) void head_kernel(
    ushortt* Ah, ushortt* Al,                 // h frags (also x write target)
    const ushortt* __restrict__ Bh, const ushortt* __restrict__ Bl,   // W1_ext frags
    const float* __restrict__ W2, const float* __restrict__ b2,
    float* __restrict__ d, unsigned* __restrict__ ctr,
    float* state, float* __restrict__ out, int t)
{
    const int mb = blockIdx.x >> 4;   // 0..15
    const int nb = blockIdx.x & 15;   // 0..15  (32 cols)
    const int w = threadIdx.x >> 6, lane = threadIdx.x & 63;
    const int quad = lane >> 4, l15 = lane & 15;
    const int mtg = mb * 16 + w * 4;

    f32x4 acc[4][2];
#pragma unroll
    for (int a = 0; a < 4; a++)
#pragma unroll
        for (int b = 0; b < 2; b++) acc[a][b] = (f32x4){0.f,0.f,0.f,0.f};

    size_t hao[4]; unsigned hbo[2];
#pragma unroll
    for (int mt = 0; mt < 4; mt++) hao[mt] = (size_t)(mtg + mt) * (KS*512) + lane * 8;
#pragma unroll
    for (int nt = 0; nt < 2; nt++) hbo[nt] = (unsigned)(nb*2 + nt) * (KS*512) + lane * 8;

    bf16x8 aC[8], bC[4], aN[8], bN[4];
    HEAD_LOADA(aC, 0); HEAD_LOADB(bC, 0);
#pragma unroll 1
    for (int ks = 0; ks < 16; ks += 2) {
        HEAD_LOADA(aN, ks+1); HEAD_LOADB(bN, ks+1);
        HEAD_MFMA(aC, bC);
        HEAD_LOADA(aC, ks+2); HEAD_LOADB(bC, ks+2);
        HEAD_MFMA(aN, bN);
    }
    HEAD_MFMA(aC, bC);

    // ---- GELU + W2 partial reduction ----
    float w2a[2], w2b[2];
#pragma unroll
    for (int nt = 0; nt < 2; nt++) {
        int col = (nb*2 + nt) * 16 + l15;
        w2a[nt] = W2[col]; w2b[nt] = W2[HH + col];
    }
    float p0[4][4], p1[4][4];
#pragma unroll
    for (int mt = 0; mt < 4; mt++)
#pragma unroll
        for (int reg = 0; reg < 4; reg++) { p0[mt][reg] = 0.f; p1[mt][reg] = 0.f; }
#pragma unroll
    for (int mt = 0; mt < 4; mt++)
#pragma unroll
        for (int nt = 0; nt < 2; nt++)
#pragma unroll
            for (int reg = 0; reg < 4; reg++) {
                float v = acc[mt][nt][reg];
                v = 0.5f * v * (1.0f + erff(v * 0.70710678118654752440f));
                p0[mt][reg] = fmaf(v, w2a[nt], p0[mt][reg]);
                p1[mt][reg] = fmaf(v, w2b[nt], p1[mt][reg]);
            }
#pragma unroll
    for (int m = 1; m < 16; m <<= 1)
#pragma unroll
        for (int mt = 0; mt < 4; mt++)
#pragma unroll
            for (int reg = 0; reg < 4; reg++) {
                p0[mt][reg] += __shfl_xor(p0[mt][reg], m, 64);
                p1[mt][reg] += __shfl_xor(p1[mt][reg], m, 64);
            }
    if (l15 == 0) {
#pragma unroll
        for (int mt = 0; mt < 4; mt++)
#pragma unroll
            for (int reg = 0; reg < 4; reg++) {
                int row = (mtg + mt) * 16 + quad * 4 + reg;
                atomicAdd(&d[row * 2], p0[mt][reg]);
                atomicAdd(&d[row * 2 + 1], p1[mt][reg]);
            }
    }

    // ---- last-block finalize ----
    __syncthreads();                    // drains this block's atomics (waitcnt before barrier)
    __shared__ unsigned lastv;
    if (threadIdx.x == 0) lastv = atomicAdd(ctr, 1u);
    __syncthreads();
    if (lastv == 255) {
        __threadfence();
#pragma unroll 1
        for (int rr = 0; rr < 16; rr++) {
            int row = rr * 256 + threadIdx.x;
            float d0 = d[row * 2]     + b2[0];
            float d1 = d[row * 2 + 1] + b2[1];
            d0 = 2.0f * tanhf(d0 * 0.5f);
            d1 = 2.0f * tanhf(d1 * 0.5f);
            float s0 = state[row * 2] + d0;
            s0 = fminf(fmaxf(s0, -90.f), 90.f);
            float s1 = state[row * 2 + 1] + d1;
            float rrm = fmodf(s1, 360.f);
            if (rrm < 0.f) rrm += 360.f;
            state[row * 2] = s0; state[row * 2 + 1] = rrm;
            float* op = out + (((size_t)(row >> 7) * HOR + t) * OO + (row & 127)) * 2;
            op[0] = s0; op[1] = rrm;
            ushortt h0, l0, h1, l1;
            splitbf(s0, h0, l0); splitbf(rrm, h1, l1);
            size_t xb = (((size_t)(row >> 4) * KS + 16) * 64 + (row & 15)) * 8;
            Ah[xb + 0] = h0; Al[xb + 0] = l0;
            Ah[xb + 1] = h1; Al[xb + 1] = l1;
        }
    }
}

// ================= prep: U = Wi*W_emb, cin = Wi*b_emb + bi =================
__global__ void fuse_kernel(const float* __restrict__ Wi_enc, const float* __restrict__ bi_enc,
                            const float* __restrict__ Wi_cell, const float* __restrict__ bi_cell,
                            const float* __restrict__ W_emb, const float* __restrict__ b_emb,
                            float* __restrict__ Ue, float* __restrict__ ce,
                            float* __restrict__ Ud, float* __restrict__ cd) {
    int idx = blockIdx.x * 256 + threadIdx.x;
    if (idx >= 2 * G3) return;
    int which = idx / G3, j = idx % G3;
    const float* Wi = which ? Wi_cell : Wi_enc;
    const float* bi = which ? bi_cell : bi_enc;
    float u0 = 0.f, u1 = 0.f, cc = bi[j];
    for (int k = 0; k < HH; k++) {
        float w = Wi[(size_t)j * HH + k];
        u0 = fmaf(w, W_emb[k * 2 + 0], u0);
        u1 = fmaf(w, W_emb[k * 2 + 1], u1);
        cc = fmaf(w, b_emb[k], cc);
    }
    float* Uo = which ? Ud : Ue;
    float* cv = which ? cd : ce;
    Uo[j * 2 + 0] = u0; Uo[j * 2 + 1] = u1; cv[j] = cc;
}

// ================= prep: pack W_ext into split-bf16 B-frags (one thread per k-octet) =================
__global__ void pack_frag(const float* __restrict__ W, const float* __restrict__ bhv,
                          const float* __restrict__ U, const float* __restrict__ cin,
                          const float* __restrict__ b1,
                          ushortt* __restrict__ Fh, ushortt* __restrict__ Fl, int N) {
    int idx = blockIdx.x * 256 + threadIdx.x;
    if (idx >= N * KS * 4) return;
    int n = idx >> 6;                 // idx / 64... careful: KS*4 = 68, not pow2
    n = idx / (KS * 4);
    int rem = idx - n * (KS * 4);
    int ks = rem >> 2, quad = rem & 3;
    int nt = n >> 4, l15 = n & 15;
    ushortt hv[8], lv[8];
#pragma unroll
    for (int s = 0; s < 8; s++) {
        int k = ks * 32 + quad * 8 + s;
        float v = 0.f;
        if (k < 512) v = W[(size_t)n * 512 + k];
        else if (k == 512) v = (U && n < 1024) ? U[n * 2 + 0] : 0.f;
        else if (k == 513) v = (U && n < 1024) ? U[n * 2 + 1] : 0.f;
        else if (k == 514) v = U ? ((n < 1024) ? (cin[n] + bhv[n]) : bhv[n]) : b1[n];
        ushortt hi, lo; splitbf(v, hi, lo);
        hv[s] = hi; lv[s] = lo;
    }
    size_t pos = ((size_t)(nt * KS + ks) * 64 + quad * 16 + l15) * 8;
#pragma unroll
    for (int s = 0; s < 8; s++) { Fh[pos + s] = hv[s]; Fl[pos + s] = lv[s]; }
}

// ================= prep: ctx = z_ctx @ W_ctx^T + b_ctx =================
__global__ void ctx_kernel(const float* __restrict__ z, const float* __restrict__ Wc,
                           const float* __restrict__ bc, float* __restrict__ ctx) {
    int idx = blockIdx.x * 256 + threadIdx.x;
    int b = idx >> 9, j = idx & 511;
    float acc = bc[j];
    const float4* zp = (const float4*)(z + (size_t)b * CTXD);
    const float4* wp = (const float4*)(Wc + (size_t)j * CTXD);
    for (int k = 0; k < CTXD / 4; k++) {
        float4 a = zp[k], ww = wp[k];
        acc = fmaf(a.x, ww.x, fmaf(a.y, ww.y, fmaf(a.z, ww.z, fmaf(a.w, ww.w, acc))));
    }
    ctx[idx] = acc;
}

// ================= init =================
__global__ void init_kernel(const float* __restrict__ traj,
                            ushortt* __restrict__ Ah0, ushortt* __restrict__ Al0,
                            ushortt* __restrict__ Ah1, ushortt* __restrict__ Al1,
                            float* __restrict__ state, float* __restrict__ d,
                            unsigned* __restrict__ ctr) {
    int b = blockIdx.x;
    if (b < 1024) {
        int item = b * 256 + threadIdx.x;
        int mt = item >> 10, ks = (item >> 6) & 15, q4 = item & 63;
        size_t pos32 = ((size_t)(mt * KS + ks)) * 256 + q4 * 4;
        uint4 z = {0u,0u,0u,0u};
        *reinterpret_cast<uint4*>(((unsigned*)Ah0) + pos32) = z;
        *reinterpret_cast<uint4*>(((unsigned*)Al0) + pos32) = z;
    } else if (b < 1040) {
        int row = (b - 1024) * 256 + threadIdx.x;
        int bi = row >> 7, o = row & 127;
        const float* tp = traj + (((size_t)bi * TT + 0) * OO + o) * 2;
        ushortt xh0, xl0, xh1, xl1;
        splitbf(tp[0], xh0, xl0); splitbf(tp[1], xh1, xl1);
        for (int qk = 0; qk < 4; qk++)
            for (int slot = 0; slot < 8; slot++) {
                size_t p = (((size_t)(row >> 4) * KS + 16) * 64 + qk * 16 + (row & 15)) * 8 + slot;
                ushortt vh0 = 0, vl0 = 0, vh1 = 0;
                if (qk == 0 && slot == 0) { vh0 = xh0; vl0 = xl0; }
                else if (qk == 0 && slot == 1) { vh0 = xh1; vl0 = xl1; }
                else if (qk == 0 && slot == 2) { vh0 = 0x3F80; vh1 = 0x3F80; }
                Ah0[p] = vh0; Al0[p] = vl0; Ah1[p] = vh1; Al1[p] = 0;
            }
        const float* sp = traj + (((size_t)bi * TT + 23) * OO + o) * 2;
        state[row * 2] = sp[0]; state[row * 2 + 1] = sp[1];
    } else if (b < 1424) {
        int i = (b - 1040) * 256 + threadIdx.x;
        float4 z = {0.f,0.f,0.f,0.f};
        reinterpret_cast<float4*>(d)[i] = z;
    } else {
        if (threadIdx.x < 48) ctr[threadIdx.x] = 0u;
    }
}

extern "C" void kernel_launch(void* const* d_in, const int* in_sizes, int n_in,
                              void* d_out, int out_size, void* d_ws, size_t ws_size,
                              hipStream_t stream) {
    const float* z_ctx   = (const float*)d_in[0];
    const float* traj    = (const float*)d_in[1];
    const float* W_emb   = (const float*)d_in[2];
    const float* b_emb   = (const float*)d_in[3];
    const float* W_ctx   = (const float*)d_in[4];
    const float* b_ctx   = (const float*)d_in[5];
    const float* Wi_enc  = (const float*)d_in[6];
    const float* Wh_enc  = (const float*)d_in[7];
    const float* bi_enc  = (const float*)d_in[8];
    const float* bh_enc  = (const float*)d_in[9];
    const float* Wi_cell = (const float*)d_in[10];
    const float* Wh_cell = (const float*)d_in[11];
    const float* bi_cell = (const float*)d_in[12];
    const float* bh_cell = (const float*)d_in[13];
    const float* W1      = (const float*)d_in[14];
    const float* b1      = (const float*)d_in[15];
    const float* W2      = (const float*)d_in[16];
    const float* b2      = (const float*)d_in[17];
    float* out = (float*)d_out;

    char* ws = (char*)d_ws;
    size_t off = 0;
    auto alloc = [&](size_t bytes) { void* p = ws + off; off += (bytes + 255) & ~(size_t)255; return p; };
    const size_t hfrag = (size_t)256 * KS * 512 * 2;
    const size_t wfrag = (size_t)96  * KS * 512 * 2;
    const size_t w1frag = (size_t)32 * KS * 512 * 2;
    ushortt* Ah0 = (ushortt*)alloc(hfrag);
    ushortt* Al0 = (ushortt*)alloc(hfrag);
    ushortt* Ah1 = (ushortt*)alloc(hfrag);
    ushortt* Al1 = (ushortt*)alloc(hfrag);
    ushortt* WheH = (ushortt*)alloc(wfrag);
    ushortt* WheL = (ushortt*)alloc(wfrag);
    ushortt* WhdH = (ushortt*)alloc(wfrag);
    ushortt* WhdL = (ushortt*)alloc(wfrag);
    ushortt* W1H  = (ushortt*)alloc(w1frag);
    ushortt* W1L  = (ushortt*)alloc(w1frag);
    float*   state = (float*)alloc((size_t)NN * 2 * 4);
    float*   ctxb  = (float*)alloc((size_t)BB * HH * 4);
    float*   Ue    = (float*)alloc((size_t)G3 * 2 * 4);
    float*   ce    = (float*)alloc((size_t)G3 * 4);
    float*   Ud    = (float*)alloc((size_t)G3 * 2 * 4);
    float*   cd    = (float*)alloc((size_t)G3 * 4);
    float*   dbuf  = (float*)alloc((size_t)HOR * NN * 2 * 4);
    unsigned* ctr  = (unsigned*)alloc(HOR * 4);

    ushortt* bufAh[2] = {Ah0, Ah1};
    ushortt* bufAl[2] = {Al0, Al1};

    fuse_kernel<<<(2 * G3 + 255) / 256, 256, 0, stream>>>(Wi_enc, bi_enc, Wi_cell, bi_cell,
                                                          W_emb, b_emb, Ue, ce, Ud, cd);
    ctx_kernel<<<(BB * HH) / 256, 256, 0, stream>>>(z_ctx, W_ctx, b_ctx, ctxb);
    pack_frag<<<(G3 * KS * 4 + 255) / 256, 256, 0, stream>>>(Wh_enc, bh_enc, Ue, ce, nullptr, WheH, WheL, G3);
    pack_frag<<<(G3 * KS * 4 + 255) / 256, 256, 0, stream>>>(Wh_cell, bh_cell, Ud, cd, nullptr, WhdH, WhdL, G3);
    pack_frag<<<(HH * KS * 4 + 255) / 256, 256, 0, stream>>>(W1, nullptr, nullptr, nullptr, b1, W1H, W1L, HH);
    init_kernel<<<1425, 256, 0, stream>>>(traj, Ah0, Al0, Ah1, Al1, state, dbuf, ctr);

    // ---- encoder: 24 fused steps ----
    for (int t = 0; t < TT; t++) {
        int rp = t & 1, wp = (t + 1) & 1;
        step_kernel<true><<<256, 256, 0, stream>>>(bufAh[rp], bufAl[rp], bufAh[wp], bufAl[wp],
                                                   WheH, WheL, Ue, ce, traj, t, ctxb);
    }
    // ---- decoder: 48 steps x (step + head) ----
    for (int t = 0; t < HOR; t++) {
        int s = TT + t;
        int rp = s & 1, wp = (s + 1) & 1;
        step_kernel<false><<<256, 256, 0, stream>>>(bufAh[rp], bufAl[rp], bufAh[wp], bufAl[wp],
                                                    WhdH, WhdL, Ud, cd, state, t, nullptr);
        head_kernel<<<256, 256, 0, stream>>>(bufAh[wp], bufAl[wp], W1H, W1L, W2, b2,
                                             dbuf + (size_t)t * NN * 2, ctr + t, state, out, t);
    }
}

// Round 5
// 4019.804 us; speedup vs baseline: 1.1119x; 1.1119x over previous
//
#include <hip/hip_runtime.h>
#include <hip/hip_bf16.h>
#include <math.h>

// Problem constants (MiniTrajectoryPredictor)
#define BB 32
#define TT 24
#define OO 128
#define HH 512
#define CTXD 256
#define HOR 48
#define NN (BB*OO)        // 4096
#define G3 (3*HH)         // 1536
#define KS 17             // k-steps of 32 (512 h + [x0,x1,1] + pad)

typedef unsigned short ushortt;
typedef __attribute__((ext_vector_type(8))) short bf16x8;
typedef __attribute__((ext_vector_type(4))) float f32x4;

// ---- bf16 split helpers ----
__device__ __forceinline__ ushortt f2bf(float x) {
    union { float f; unsigned u; } v; v.f = x;
    unsigned r = v.u + 0x7FFF + ((v.u >> 16) & 1);
    return (ushortt)(r >> 16);
}
__device__ __forceinline__ float bf2f(ushortt b) {
    union { unsigned u; float f; } v; v.u = ((unsigned)b) << 16;
    return v.f;
}
__device__ __forceinline__ void splitbf(float x, ushortt& hi, ushortt& lo) {
    hi = f2bf(x);
    lo = f2bf(x - bf2f(hi));
}
__device__ __forceinline__ float sigm(float x) { return 1.f / (1.f + __expf(-x)); }
__device__ __forceinline__ float tanh_fast(float x) {
    float xc = fminf(fmaxf(x, -10.f), 10.f);
    float e = __expf(2.f * xc);
    return (e - 1.f) / (e + 1.f);
}

// Fragment layout (verified R2/R3): element (row r, k) of a 16-row tile lives at
// lane = ((k%32)>>3)*16 + (r%16), slot = k%8; buffer [tile][ks][lane][slot] u16.
// C/D: col = lane&15, row = (lane>>4)*4 + reg.
//
// XCD locality (R5): row-group mb is pinned to XCD mb%8 by putting mb in the LOW
// bits of blockIdx in EVERY kernel that touches h-frags. h tiles for mb are then
// written and re-read on the same XCD's L2 across all 72 steps.

// ================= fused gh-GEMM + GRU step =================
// Wave tile: 64 rows (4 m-tiles) x 96 cols (3 gates x 32 j = 6 n-tiles).
// Block: 4 row-stacked waves = 256 rows x 32 j-cols. Grid 256 (1 block/CU).

#define STEP_LOADA(Ad, ksv) do { const unsigned ko = (unsigned)(ksv) * 512; \
  _Pragma("unroll") for (int m_ = 0; m_ < 4; m_++) { \
    Ad[m_*2+0] = *reinterpret_cast<const bf16x8*>(RAh + ao[m_] + ko); \
    Ad[m_*2+1] = *reinterpret_cast<const bf16x8*>(RAl + ao[m_] + ko); \
  } } while(0)
#define STEP_LOADB(Bd, ksv) do { const unsigned ko = (unsigned)(ksv) * 512; \
  _Pragma("unroll") for (int i_ = 0; i_ < 6; i_++) { \
    Bd[i_*2+0] = *reinterpret_cast<const bf16x8*>(Bh + bo[i_] + ko); \
    Bd[i_*2+1] = *reinterpret_cast<const bf16x8*>(Bl + bo[i_] + ko); \
  } } while(0)
#define STEP_MFMA(Av, Bv) do { \
  _Pragma("unroll") for (int m_ = 0; m_ < 4; m_++) \
  _Pragma("unroll") for (int i_ = 0; i_ < 6; i_++) \
    acc[m_][i_] = __builtin_amdgcn_mfma_f32_16x16x32_bf16(Av[m_*2+0], Bv[i_*2+0], acc[m_][i_], 0,0,0); \
  _Pragma("unroll") for (int m_ = 0; m_ < 4; m_++) \
  _Pragma("unroll") for (int i_ = 0; i_ < 6; i_++) \
    acc[m_][i_] = __builtin_amdgcn_mfma_f32_16x16x32_bf16(Av[m_*2+0], Bv[i_*2+1], acc[m_][i_], 0,0,0); \
  _Pragma("unroll") for (int m_ = 0; m_ < 4; m_++) \
  _Pragma("unroll") for (int i_ = 0; i_ < 6; i_++) \
    acc[m_][i_] = __builtin_amdgcn_mfma_f32_16x16x32_bf16(Av[m_*2+1], Bv[i_*2+0], acc[m_][i_], 0,0,0); \
  } while(0)

template<bool ENC>
__global__ __launch_bounds__(256, 1) void step_kernel(
    const ushortt* __restrict__ RAh, const ushortt* __restrict__ RAl,   // read h frags
    ushortt* __restrict__ WAh, ushortt* __restrict__ WAl,               // write h frags
    const ushortt* __restrict__ Bh, const ushortt* __restrict__ Bl,     // Wh_ext frags
    const float* __restrict__ U, const float* __restrict__ cin,
    const float* __restrict__ xsrc, int t, const float* __restrict__ ctx)
{
    __shared__ float hbuf[256 * 36];   // stride 36: float4-aligned rows, 2-way banks (free)
    const int mb = blockIdx.x & 15;    // LOW bits -> XCD = mb%8 (row-pinned)
    const int jb = blockIdx.x >> 4;    // 0..15  (32 j-cols per gate)
    const int w = threadIdx.x >> 6, lane = threadIdx.x & 63;
    const int quad = lane >> 4, l15 = lane & 15;
    const int mtg = mb * 16 + w * 4;   // wave's 4 global m-tiles

    f32x4 acc[4][6];
#pragma unroll
    for (int a = 0; a < 4; a++)
#pragma unroll
        for (int b = 0; b < 6; b++) acc[a][b] = (f32x4){0.f,0.f,0.f,0.f};

    unsigned ao[4], bo[6];
#pragma unroll
    for (int mt = 0; mt < 4; mt++) ao[mt] = (unsigned)(mtg + mt) * (KS*512) + lane * 8;
#pragma unroll
    for (int g = 0; g < 3; g++)
#pragma unroll
        for (int jt = 0; jt < 2; jt++)
            bo[g*2+jt] = (unsigned)(g*32 + jb*2 + jt) * (KS*512) + lane * 8;

    bf16x8 aC[8], bC[12], aN[8], bN[12];
    STEP_LOADA(aC, 0); STEP_LOADB(bC, 0);
#pragma unroll 1
    for (int ks = 0; ks < 16; ks += 2) {
        STEP_LOADA(aN, ks+1); STEP_LOADB(bN, ks+1);
        STEP_MFMA(aC, bC);
        STEP_LOADA(aC, ks+2); STEP_LOADB(bC, ks+2);
        STEP_MFMA(aN, bN);
    }
    STEP_MFMA(aC, bC);

    // ---------------- GRU epilogue ----------------
    const int jlo = jb * 32;
    float u0[2], u1[2], cc[2];
#pragma unroll
    for (int jt = 0; jt < 2; jt++) {
        int j = jlo + jt*16 + l15;
        u0[jt] = U[(1024 + j) * 2];
        u1[jt] = U[(1024 + j) * 2 + 1];
        cc[jt] = cin[1024 + j];
    }
    float x0v[4][4], x1v[4][4];
#pragma unroll
    for (int mt = 0; mt < 4; mt++)
#pragma unroll
        for (int reg = 0; reg < 4; reg++) {
            int row = (mtg + mt) * 16 + quad * 4 + reg;
            const float* p;
            if (ENC) p = xsrc + (((size_t)(row >> 7) * TT + t) * OO + (row & 127)) * 2;
            else     p = xsrc + (size_t)row * 2;
            x0v[mt][reg] = p[0]; x1v[mt][reg] = p[1];
        }
#pragma unroll
    for (int mt = 0; mt < 4; mt++)
#pragma unroll
        for (int jt = 0; jt < 2; jt++) {
            int qk = jt*2 + (l15 >> 3), slot = l15 & 7;
#pragma unroll
            for (int reg = 0; reg < 4; reg++) {
                int row = (mtg + mt) * 16 + quad * 4 + reg;
                float pr = acc[mt][0*2+jt][reg];
                float pz = acc[mt][1*2+jt][reg];
                float hn = acc[mt][2*2+jt][reg];
                unsigned pos = ((unsigned)((mtg + mt) * KS + jb) * 64 + qk*16 + quad*4 + reg) * 8 + slot;
                float hold = bf2f(RAh[pos]) + bf2f(RAl[pos]);
                float inn = fmaf(x1v[mt][reg], u1[jt], fmaf(x0v[mt][reg], u0[jt], cc[jt]));
                float rg = sigm(pr), zg = sigm(pz);
                float nn = tanh_fast(inn + rg * hn);
                float h = (1.f - zg) * nn + zg * hold;
                if (ENC && t == TT - 1) h += ctx[(size_t)(row >> 7) * HH + jlo + jt*16 + l15];
                hbuf[(w*64 + mt*16 + quad*4 + reg) * 36 + jt*16 + l15] = h;
            }
        }
    __syncthreads();
    // repack LDS tile (256 rows x 32 j) -> A-frags ks == jb of write buffer
#pragma unroll
    for (int rr = 0; rr < 4; rr++) {
        int fr = threadIdx.x + 256 * rr;       // 0..1023
        int mt16 = fr >> 6, fl = fr & 63;
        int qk = fl >> 4, rloc = mt16 * 16 + (fl & 15);
        const float4 v0 = *reinterpret_cast<const float4*>(&hbuf[rloc * 36 + qk * 8]);
        const float4 v1 = *reinterpret_cast<const float4*>(&hbuf[rloc * 36 + qk * 8 + 4]);
        float src[8] = {v0.x, v0.y, v0.z, v0.w, v1.x, v1.y, v1.z, v1.w};
        bf16x8 hv, lv;
#pragma unroll
        for (int s = 0; s < 8; s++) {
            ushortt hi, lo; splitbf(src[s], hi, lo);
            hv[s] = (short)hi; lv[s] = (short)lo;
        }
        unsigned base = ((unsigned)((mb*16 + mt16) * KS + jb) * 64 + fl) * 8;
        *reinterpret_cast<bf16x8*>(WAh + base) = hv;
        *reinterpret_cast<bf16x8*>(WAl + base) = lv;
    }
    // encoder write-ahead: next step's x into write buffer ks=16 (slots 0,1)
    if (ENC && jb == 0) {
        int row = mb * 256 + threadIdx.x;
        int tn = (t < TT - 1) ? (t + 1) : (TT - 1);
        const float* p = xsrc + (((size_t)(row >> 7) * TT + tn) * OO + (row & 127)) * 2;
        ushortt h0, l0, h1, l1;
        splitbf(p[0], h0, l0); splitbf(p[1], h1, l1);
        unsigned xb = ((unsigned)((row >> 4) * KS + 16) * 64 + (row & 15)) * 8;
        WAh[xb + 0] = h0; WAl[xb + 0] = l0;
        WAh[xb + 1] = h1; WAl[xb + 1] = l1;
    }
}

// ================= fused head: t1 = gelu(h@W1^T + b1); d += t1@W2^T; last block finalizes =================
// Wave 64 rows x 32 cols (4 mt x 2 nt). Block 256 rows x 32 cols. Grid 256, mb in LOW bits.
#define HEAD_LOADA(Ad, ksv) do { const unsigned ko = (unsigned)(ksv) * 512; \
  _Pragma("unroll") for (int m_ = 0; m_ < 4; m_++) { \
    Ad[m_*2+0] = *reinterpret_cast<const bf16x8*>(Ah + hao[m_] + ko); \
    Ad[m_*2+1] = *reinterpret_cast<const bf16x8*>(Al + hao[m_] + ko); \
  } } while(0)
#define HEAD_LOADB(Bd, ksv) do { const unsigned ko = (unsigned)(ksv) * 512; \
  _Pragma("unroll") for (int n_ = 0; n_ < 2; n_++) { \
    Bd[n_*2+0] = *reinterpret_cast<const bf16x8*>(Bh + hbo[n_] + ko); \
    Bd[n_*2+1] = *reinterpret_cast<const bf16x8*>(Bl + hbo[n_] + ko); \
  } } while(0)
#define HEAD_MFMA(Av, Bv) do { \
  _Pragma("unroll") for (int m_ = 0; m_ < 4; m_++) \
  _Pragma("unroll") for (int n_ = 0; n_ < 2; n_++) { \
    acc[m_][n_] = __builtin_amdgcn_mfma_f32_16x16x32_bf16(Av[m_*2+0], Bv[n_*2+0], acc[m_][n_], 0,0,0); \
    acc[m_][n_] = __builtin_amdgcn_mfma_f32_16x16x32_bf16(Av[m_*2+0], Bv[n_*2+1], acc[m_][n_], 0,0,0); \
    acc[m_][n_] = __builtin_amdgcn_mfma_f32_16x16x32_bf16(Av[m_*2+1], Bv[n_*2+0], acc[m_][n_], 0,0,0); \
  } } while(0)

__global__ __launch_bounds__(256, 1) void head_kernel(
    ushortt* Ah, ushortt* Al,                 // h frags (also x write target)
    const ushortt* __restrict__ Bh, const ushortt* __restrict__ Bl,   // W1_ext frags
    const float* __restrict__ W2, const float* __restrict__ b2,
    float* __restrict__ d, unsigned* __restrict__ ctr,
    float* state, float* __restrict__ out, int t)
{
    const int mb = blockIdx.x & 15;   // LOW bits -> XCD = mb%8 (matches step_kernel)
    const int nb = blockIdx.x >> 4;   // 0..15  (32 cols)
    const int w = threadIdx.x >> 6, lane = threadIdx.x & 63;
    const int quad = lane >> 4, l15 = lane & 15;
    const int mtg = mb * 16 + w * 4;

    f32x4 acc[4][2];
#pragma unroll
    for (int a = 0; a < 4; a++)
#pragma unroll
        for (int b = 0; b < 2; b++) acc[a][b] = (f32x4){0.f,0.f,0.f,0.f};

    unsigned hao[4], hbo[2];
#pragma unroll
    for (int mt = 0; mt < 4; mt++) hao[mt] = (unsigned)(mtg + mt) * (KS*512) + lane * 8;
#pragma unroll
    for (int nt = 0; nt < 2; nt++) hbo[nt] = (unsigned)(nb*2 + nt) * (KS*512) + lane * 8;

    bf16x8 aC[8], bC[4], aN[8], bN[4];
    HEAD_LOADA(aC, 0); HEAD_LOADB(bC, 0);
#pragma unroll 1
    for (int ks = 0; ks < 16; ks += 2) {
        HEAD_LOADA(aN, ks+1); HEAD_LOADB(bN, ks+1);
        HEAD_MFMA(aC, bC);
        HEAD_LOADA(aC, ks+2); HEAD_LOADB(bC, ks+2);
        HEAD_MFMA(aN, bN);
    }
    HEAD_MFMA(aC, bC);

    // ---- GELU + W2 partial reduction ----
    float w2a[2], w2b[2];
#pragma unroll
    for (int nt = 0; nt < 2; nt++) {
        int col = (nb*2 + nt) * 16 + l15;
        w2a[nt] = W2[col]; w2b[nt] = W2[HH + col];
    }
    float p0[4][4], p1[4][4];
#pragma unroll
    for (int mt = 0; mt < 4; mt++)
#pragma unroll
        for (int reg = 0; reg < 4; reg++) { p0[mt][reg] = 0.f; p1[mt][reg] = 0.f; }
#pragma unroll
    for (int mt = 0; mt < 4; mt++)
#pragma unroll
        for (int nt = 0; nt < 2; nt++)
#pragma unroll
            for (int reg = 0; reg < 4; reg++) {
                float v = acc[mt][nt][reg];
                v = 0.5f * v * (1.0f + erff(v * 0.70710678118654752440f));
                p0[mt][reg] = fmaf(v, w2a[nt], p0[mt][reg]);
                p1[mt][reg] = fmaf(v, w2b[nt], p1[mt][reg]);
            }
#pragma unroll
    for (int m = 1; m < 16; m <<= 1)
#pragma unroll
        for (int mt = 0; mt < 4; mt++)
#pragma unroll
            for (int reg = 0; reg < 4; reg++) {
                p0[mt][reg] += __shfl_xor(p0[mt][reg], m, 64);
                p1[mt][reg] += __shfl_xor(p1[mt][reg], m, 64);
            }
    if (l15 == 0) {
#pragma unroll
        for (int mt = 0; mt < 4; mt++)
#pragma unroll
            for (int reg = 0; reg < 4; reg++) {
                int row = (mtg + mt) * 16 + quad * 4 + reg;
                atomicAdd(&d[row * 2], p0[mt][reg]);
                atomicAdd(&d[row * 2 + 1], p1[mt][reg]);
            }
    }

    // ---- last-block finalize ----
    __syncthreads();                    // drains this block's atomics
    __shared__ unsigned lastv;
    if (threadIdx.x == 0) lastv = atomicAdd(ctr, 1u);
    __syncthreads();
    if (lastv == 255) {
        __threadfence();
#pragma unroll 1
        for (int rr = 0; rr < 16; rr++) {
            int row = rr * 256 + threadIdx.x;
            float d0 = d[row * 2]     + b2[0];
            float d1 = d[row * 2 + 1] + b2[1];
            d0 = 2.0f * tanhf(d0 * 0.5f);
            d1 = 2.0f * tanhf(d1 * 0.5f);
            float s0 = state[row * 2] + d0;
            s0 = fminf(fmaxf(s0, -90.f), 90.f);
            float s1 = state[row * 2 + 1] + d1;
            float rrm = fmodf(s1, 360.f);
            if (rrm < 0.f) rrm += 360.f;
            state[row * 2] = s0; state[row * 2 + 1] = rrm;
            float* op = out + (((size_t)(row >> 7) * HOR + t) * OO + (row & 127)) * 2;
            op[0] = s0; op[1] = rrm;
            ushortt h0, l0, h1, l1;
            splitbf(s0, h0, l0); splitbf(rrm, h1, l1);
            unsigned xb = ((unsigned)((row >> 4) * KS + 16) * 64 + (row & 15)) * 8;
            Ah[xb + 0] = h0; Al[xb + 0] = l0;
            Ah[xb + 1] = h1; Al[xb + 1] = l1;
        }
    }
}

// ================= prep: U = Wi*W_emb, cin = Wi*b_emb + bi =================
__global__ void fuse_kernel(const float* __restrict__ Wi_enc, const float* __restrict__ bi_enc,
                            const float* __restrict__ Wi_cell, const float* __restrict__ bi_cell,
                            const float* __restrict__ W_emb, const float* __restrict__ b_emb,
                            float* __restrict__ Ue, float* __restrict__ ce,
                            float* __restrict__ Ud, float* __restrict__ cd) {
    int idx = blockIdx.x * 256 + threadIdx.x;
    if (idx >= 2 * G3) return;
    int which = idx / G3, j = idx % G3;
    const float* Wi = which ? Wi_cell : Wi_enc;
    const float* bi = which ? bi_cell : bi_enc;
    float u0 = 0.f, u1 = 0.f, cc = bi[j];
    for (int k = 0; k < HH; k++) {
        float w = Wi[(size_t)j * HH + k];
        u0 = fmaf(w, W_emb[k * 2 + 0], u0);
        u1 = fmaf(w, W_emb[k * 2 + 1], u1);
        cc = fmaf(w, b_emb[k], cc);
    }
    float* Uo = which ? Ud : Ue;
    float* cv = which ? cd : ce;
    Uo[j * 2 + 0] = u0; Uo[j * 2 + 1] = u1; cv[j] = cc;
}

// ================= prep: pack W_ext into split-bf16 B-frags (one thread per k-octet) =================
__global__ void pack_frag(const float* __restrict__ W, const float* __restrict__ bhv,
                          const float* __restrict__ U, const float* __restrict__ cin,
                          const float* __restrict__ b1,
                          ushortt* __restrict__ Fh, ushortt* __restrict__ Fl, int N) {
    int idx = blockIdx.x * 256 + threadIdx.x;
    if (idx >= N * KS * 4) return;
    int n = idx / (KS * 4);
    int rem = idx - n * (KS * 4);
    int ks = rem >> 2, quad = rem & 3;
    int nt = n >> 4, l15 = n & 15;
    ushortt hv[8], lv[8];
#pragma unroll
    for (int s = 0; s < 8; s++) {
        int k = ks * 32 + quad * 8 + s;
        float v = 0.f;
        if (k < 512) v = W[(size_t)n * 512 + k];
        else if (k == 512) v = (U && n < 1024) ? U[n * 2 + 0] : 0.f;
        else if (k == 513) v = (U && n < 1024) ? U[n * 2 + 1] : 0.f;
        else if (k == 514) v = U ? ((n < 1024) ? (cin[n] + bhv[n]) : bhv[n]) : b1[n];
        ushortt hi, lo; splitbf(v, hi, lo);
        hv[s] = hi; lv[s] = lo;
    }
    size_t pos = ((size_t)(nt * KS + ks) * 64 + quad * 16 + l15) * 8;
#pragma unroll
    for (int s = 0; s < 8; s++) { Fh[pos + s] = hv[s]; Fl[pos + s] = lv[s]; }
}

// ================= prep: ctx = z_ctx @ W_ctx^T + b_ctx =================
__global__ void ctx_kernel(const float* __restrict__ z, const float* __restrict__ Wc,
                           const float* __restrict__ bc, float* __restrict__ ctx) {
    int idx = blockIdx.x * 256 + threadIdx.x;
    int b = idx >> 9, j = idx & 511;
    float acc = bc[j];
    const float4* zp = (const float4*)(z + (size_t)b * CTXD);
    const float4* wp = (const float4*)(Wc + (size_t)j * CTXD);
    for (int k = 0; k < CTXD / 4; k++) {
        float4 a = zp[k], ww = wp[k];
        acc = fmaf(a.x, ww.x, fmaf(a.y, ww.y, fmaf(a.z, ww.z, fmaf(a.w, ww.w, acc))));
    }
    ctx[idx] = acc;
}

// ================= init =================
__global__ void init_kernel(const float* __restrict__ traj,
                            ushortt* __restrict__ Ah0, ushortt* __restrict__ Al0,
                            ushortt* __restrict__ Ah1, ushortt* __restrict__ Al1,
                            float* __restrict__ state, float* __restrict__ d,
                            unsigned* __restrict__ ctr) {
    int b = blockIdx.x;
    if (b < 1024) {
        int item = b * 256 + threadIdx.x;
        int mt = item >> 10, ks = (item >> 6) & 15, q4 = item & 63;
        size_t pos32 = ((size_t)(mt * KS + ks)) * 256 + q4 * 4;
        uint4 z = {0u,0u,0u,0u};
        *reinterpret_cast<uint4*>(((unsigned*)Ah0) + pos32) = z;
        *reinterpret_cast<uint4*>(((unsigned*)Al0) + pos32) = z;
    } else if (b < 1040) {
        int row = (b - 1024) * 256 + threadIdx.x;
        int bi = row >> 7, o = row & 127;
        const float* tp = traj + (((size_t)bi * TT + 0) * OO + o) * 2;
        ushortt xh0, xl0, xh1, xl1;
        splitbf(tp[0], xh0, xl0); splitbf(tp[1], xh1, xl1);
        for (int qk = 0; qk < 4; qk++)
            for (int slot = 0; slot < 8; slot++) {
                size_t p = (((size_t)(row >> 4) * KS + 16) * 64 + qk * 16 + (row & 15)) * 8 + slot;
                ushortt vh0 = 0, vl0 = 0, vh1 = 0;
                if (qk == 0 && slot == 0) { vh0 = xh0; vl0 = xl0; }
                else if (qk == 0 && slot == 1) { vh0 = xh1; vl0 = xl1; }
                else if (qk == 0 && slot == 2) { vh0 = 0x3F80; vh1 = 0x3F80; }
                Ah0[p] = vh0; Al0[p] = vl0; Ah1[p] = vh1; Al1[p] = 0;
            }
        const float* sp = traj + (((size_t)bi * TT + 23) * OO + o) * 2;
        state[row * 2] = sp[0]; state[row * 2 + 1] = sp[1];
    } else if (b < 1424) {
        int i = (b - 1040) * 256 + threadIdx.x;
        float4 z = {0.f,0.f,0.f,0.f};
        reinterpret_cast<float4*>(d)[i] = z;
    } else {
        if (threadIdx.x < 48) ctr[threadIdx.x] = 0u;
    }
}

extern "C" void kernel_launch(void* const* d_in, const int* in_sizes, int n_in,
                              void* d_out, int out_size, void* d_ws, size_t ws_size,
                              hipStream_t stream) {
    const float* z_ctx   = (const float*)d_in[0];
    const float* traj    = (const float*)d_in[1];
    const float* W_emb   = (const float*)d_in[2];
    const float* b_emb   = (const float*)d_in[3];
    const float* W_ctx   = (const float*)d_in[4];
    const float* b_ctx   = (const float*)d_in[5];
    const float* Wi_enc  = (const float*)d_in[6];
    const float* Wh_enc  = (const float*)d_in[7];
    const float* bi_enc  = (const float*)d_in[8];
    const float* bh_enc  = (const float*)d_in[9];
    const float* Wi_cell = (const float*)d_in[10];
    const float* Wh_cell = (const float*)d_in[11];
    const float* bi_cell = (const float*)d_in[12];
    const float* bh_cell = (const float*)d_in[13];
    const float* W1      = (const float*)d_in[14];
    const float* b1      = (const float*)d_in[15];
    const float* W2      = (const float*)d_in[16];
    const float* b2      = (const float*)d_in[17];
    float* out = (float*)d_out;

    char* ws = (char*)d_ws;
    size_t off = 0;
    auto alloc = [&](size_t bytes) { void* p = ws + off; off += (bytes + 255) & ~(size_t)255; return p; };
    const size_t hfrag = (size_t)256 * KS * 512 * 2;
    const size_t wfrag = (size_t)96  * KS * 512 * 2;
    const size_t w1frag = (size_t)32 * KS * 512 * 2;
    ushortt* Ah0 = (ushortt*)alloc(hfrag);
    ushortt* Al0 = (ushortt*)alloc(hfrag);
    ushortt* Ah1 = (ushortt*)alloc(hfrag);
    ushortt* Al1 = (ushortt*)alloc(hfrag);
    ushortt* WheH = (ushortt*)alloc(wfrag);
    ushortt* WheL = (ushortt*)alloc(wfrag);
    ushortt* WhdH = (ushortt*)alloc(wfrag);
    ushortt* WhdL = (ushortt*)alloc(wfrag);
    ushortt* W1H  = (ushortt*)alloc(w1frag);
    ushortt* W1L  = (ushortt*)alloc(w1frag);
    float*   state = (float*)alloc((size_t)NN * 2 * 4);
    float*   ctxb  = (float*)alloc((size_t)BB * HH * 4);
    float*   Ue    = (float*)alloc((size_t)G3 * 2 * 4);
    float*   ce    = (float*)alloc((size_t)G3 * 4);
    float*   Ud    = (float*)alloc((size_t)G3 * 2 * 4);
    float*   cd    = (float*)alloc((size_t)G3 * 4);
    float*   dbuf  = (float*)alloc((size_t)HOR * NN * 2 * 4);
    unsigned* ctr  = (unsigned*)alloc(HOR * 4);

    ushortt* bufAh[2] = {Ah0, Ah1};
    ushortt* bufAl[2] = {Al0, Al1};

    fuse_kernel<<<(2 * G3 + 255) / 256, 256, 0, stream>>>(Wi_enc, bi_enc, Wi_cell, bi_cell,
                                                          W_emb, b_emb, Ue, ce, Ud, cd);
    ctx_kernel<<<(BB * HH) / 256, 256, 0, stream>>>(z_ctx, W_ctx, b_ctx, ctxb);
    pack_frag<<<(G3 * KS * 4 + 255) / 256, 256, 0, stream>>>(Wh_enc, bh_enc, Ue, ce, nullptr, WheH, WheL, G3);
    pack_frag<<<(G3 * KS * 4 + 255) / 256, 256, 0, stream>>>(Wh_cell, bh_cell, Ud, cd, nullptr, WhdH, WhdL, G3);
    pack_frag<<<(HH * KS * 4 + 255) / 256, 256, 0, stream>>>(W1, nullptr, nullptr, nullptr, b1, W1H, W1L, HH);
    init_kernel<<<1425, 256, 0, stream>>>(traj, Ah0, Al0, Ah1, Al1, state, dbuf, ctr);

    // ---- encoder: 24 fused steps ----
    for (int t = 0; t < TT; t++) {
        int rp = t & 1, wp = (t + 1) & 1;
        step_kernel<true><<<256, 256, 0, stream>>>(bufAh[rp], bufAl[rp], bufAh[wp], bufAl[wp],
                                                   WheH, WheL, Ue, ce, traj, t, ctxb);
    }
    // ---- decoder: 48 steps x (step + head) ----
    for (int t = 0; t < HOR; t++) {
        int s = TT + t;
        int rp = s & 1, wp = (s + 1) & 1;
        step_kernel<false><<<256, 256, 0, stream>>>(bufAh[rp], bufAl[rp], bufAh[wp], bufAl[wp],
                                                    WhdH, WhdL, Ud, cd, state, t, nullptr);
        head_kernel<<<256, 256, 0, stream>>>(bufAh[wp], bufAl[wp], W1H, W1L, W2, b2,
                                             dbuf + (size_t)t * NN * 2, ctr + t, state, out, t);
    }
}

// Round 6
// 3501.208 us; speedup vs baseline: 1.2766x; 1.1481x over previous
//
#include <hip/hip_runtime.h>
#include <hip/hip_bf16.h>
#include <math.h>

// Problem constants (MiniTrajectoryPredictor)
#define BB 32
#define TT 24
#define OO 128
#define HH 512
#define CTXD 256
#define HOR 48
#define NN (BB*OO)        // 4096
#define G3 (3*HH)         // 1536
#define KS 17             // k-steps of 32 (512 h + [x0,x1,1] + pad)

typedef unsigned short ushortt;
typedef __attribute__((ext_vector_type(8))) short bf16x8;
typedef __attribute__((ext_vector_type(4))) float f32x4;

// ---- bf16 split helpers ----
__device__ __forceinline__ ushortt f2bf(float x) {
    union { float f; unsigned u; } v; v.f = x;
    unsigned r = v.u + 0x7FFF + ((v.u >> 16) & 1);
    return (ushortt)(r >> 16);
}
__device__ __forceinline__ float bf2f(ushortt b) {
    union { unsigned u; float f; } v; v.u = ((unsigned)b) << 16;
    return v.f;
}
__device__ __forceinline__ void splitbf(float x, ushortt& hi, ushortt& lo) {
    hi = f2bf(x);
    lo = f2bf(x - bf2f(hi));
}
__device__ __forceinline__ float sigm(float x) { return 1.f / (1.f + __expf(-x)); }
__device__ __forceinline__ float tanh_fast(float x) {
    float xc = fminf(fmaxf(x, -10.f), 10.f);
    float e = __expf(2.f * xc);
    return (e - 1.f) / (e + 1.f);
}

// Fragment layout (verified R2+): element (row r, k) of a 16-row tile lives at
// lane = ((k%32)>>3)*16 + (r%16), slot = k%8; buffer [tile][ks][lane][slot] u16.
// C/D: col = lane&15, row = (lane>>4)*4 + reg.
//
// R6 design notes:
// - Occupancy > tile intensity in this latency-bound regime (R3 vs R4/R5 evidence):
//   block = 128 rows x 32 j, wave = 2 mt x 6 nt, 2 blocks/CU.
// - XCD pinning kept: mb in LOW bits of blockIdx -> XCD = mb%8; A-frag producer
//   and consumers stay on one XCD (helps LLC locality even with L2 inval at
//   kernel boundaries).

// ================= fused gh-GEMM + GRU step =================
#define STEP_LOADA(Ad, ksv) do { const unsigned ko = (unsigned)(ksv) * 512; \
  _Pragma("unroll") for (int m_ = 0; m_ < 2; m_++) { \
    Ad[m_*2+0] = *reinterpret_cast<const bf16x8*>(RAh + ao[m_] + ko); \
    Ad[m_*2+1] = *reinterpret_cast<const bf16x8*>(RAl + ao[m_] + ko); \
  } } while(0)
#define STEP_LOADB(Bd, ksv) do { const unsigned ko = (unsigned)(ksv) * 512; \
  _Pragma("unroll") for (int i_ = 0; i_ < 6; i_++) { \
    Bd[i_*2+0] = *reinterpret_cast<const bf16x8*>(Bh + bo[i_] + ko); \
    Bd[i_*2+1] = *reinterpret_cast<const bf16x8*>(Bl + bo[i_] + ko); \
  } } while(0)
#define STEP_MFMA(Av, Bv) do { \
  _Pragma("unroll") for (int m_ = 0; m_ < 2; m_++) \
  _Pragma("unroll") for (int i_ = 0; i_ < 6; i_++) \
    acc[m_][i_] = __builtin_amdgcn_mfma_f32_16x16x32_bf16(Av[m_*2+0], Bv[i_*2+0], acc[m_][i_], 0,0,0); \
  _Pragma("unroll") for (int m_ = 0; m_ < 2; m_++) \
  _Pragma("unroll") for (int i_ = 0; i_ < 6; i_++) \
    acc[m_][i_] = __builtin_amdgcn_mfma_f32_16x16x32_bf16(Av[m_*2+0], Bv[i_*2+1], acc[m_][i_], 0,0,0); \
  _Pragma("unroll") for (int m_ = 0; m_ < 2; m_++) \
  _Pragma("unroll") for (int i_ = 0; i_ < 6; i_++) \
    acc[m_][i_] = __builtin_amdgcn_mfma_f32_16x16x32_bf16(Av[m_*2+1], Bv[i_*2+0], acc[m_][i_], 0,0,0); \
  } while(0)

template<bool ENC>
__global__ __launch_bounds__(256, 2) void step_kernel(
    const ushortt* __restrict__ RAh, const ushortt* __restrict__ RAl,   // read h frags
    ushortt* __restrict__ WAh, ushortt* __restrict__ WAl,               // write h frags
    const ushortt* __restrict__ Bh, const ushortt* __restrict__ Bl,     // Wh_ext frags
    const float* __restrict__ U, const float* __restrict__ cin,
    const float* __restrict__ xsrc, int t, const float* __restrict__ ctx)
{
    __shared__ float hbuf[128 * 36];   // 18 KB; stride 36: float4-aligned, 2-way banks (free)
    const int mb = blockIdx.x & 31;    // LOW bits -> XCD = mb%8 (row-pinned), 128 rows each
    const int jb = blockIdx.x >> 5;    // 0..15  (32 j-cols per gate)
    const int w = threadIdx.x >> 6, lane = threadIdx.x & 63;
    const int quad = lane >> 4, l15 = lane & 15;
    const int mtg = mb * 8 + w * 2;    // wave's 2 global m-tiles

    f32x4 acc[2][6];
#pragma unroll
    for (int a = 0; a < 2; a++)
#pragma unroll
        for (int b = 0; b < 6; b++) acc[a][b] = (f32x4){0.f,0.f,0.f,0.f};

    unsigned ao[2], bo[6];
#pragma unroll
    for (int mt = 0; mt < 2; mt++) ao[mt] = (unsigned)(mtg + mt) * (KS*512) + lane * 8;
#pragma unroll
    for (int g = 0; g < 3; g++)
#pragma unroll
        for (int jt = 0; jt < 2; jt++)
            bo[g*2+jt] = (unsigned)(g*32 + jb*2 + jt) * (KS*512) + lane * 8;

    bf16x8 aC[4], bC[12], aN[4], bN[12];
    STEP_LOADA(aC, 0); STEP_LOADB(bC, 0);
#pragma unroll 1
    for (int ks = 0; ks < 16; ks += 2) {
        STEP_LOADA(aN, ks+1); STEP_LOADB(bN, ks+1);
        STEP_MFMA(aC, bC);
        STEP_LOADA(aC, ks+2); STEP_LOADB(bC, ks+2);
        STEP_MFMA(aN, bN);
    }
    STEP_MFMA(aC, bC);

    // ---------------- GRU epilogue ----------------
    const int jlo = jb * 32;
    float u0[2], u1[2], cc[2];
#pragma unroll
    for (int jt = 0; jt < 2; jt++) {
        int j = jlo + jt*16 + l15;
        u0[jt] = U[(1024 + j) * 2];
        u1[jt] = U[(1024 + j) * 2 + 1];
        cc[jt] = cin[1024 + j];
    }
    float x0v[2][4], x1v[2][4];
#pragma unroll
    for (int mt = 0; mt < 2; mt++)
#pragma unroll
        for (int reg = 0; reg < 4; reg++) {
            int row = (mtg + mt) * 16 + quad * 4 + reg;
            const float* p;
            if (ENC) p = xsrc + (((size_t)(row >> 7) * TT + t) * OO + (row & 127)) * 2;
            else     p = xsrc + (size_t)row * 2;
            x0v[mt][reg] = p[0]; x1v[mt][reg] = p[1];
        }
#pragma unroll
    for (int mt = 0; mt < 2; mt++)
#pragma unroll
        for (int jt = 0; jt < 2; jt++) {
            int qk = jt*2 + (l15 >> 3), slot = l15 & 7;
#pragma unroll
            for (int reg = 0; reg < 4; reg++) {
                int row = (mtg + mt) * 16 + quad * 4 + reg;
                float pr = acc[mt][0*2+jt][reg];
                float pz = acc[mt][1*2+jt][reg];
                float hn = acc[mt][2*2+jt][reg];
                unsigned pos = ((unsigned)((mtg + mt) * KS + jb) * 64 + qk*16 + quad*4 + reg) * 8 + slot;
                float hold = bf2f(RAh[pos]) + bf2f(RAl[pos]);
                float inn = fmaf(x1v[mt][reg], u1[jt], fmaf(x0v[mt][reg], u0[jt], cc[jt]));
                float rg = sigm(pr), zg = sigm(pz);
                float nn = tanh_fast(inn + rg * hn);
                float h = (1.f - zg) * nn + zg * hold;
                if (ENC && t == TT - 1) h += ctx[(size_t)(row >> 7) * HH + jlo + jt*16 + l15];
                hbuf[(w*32 + mt*16 + quad*4 + reg) * 36 + jt*16 + l15] = h;
            }
        }
    __syncthreads();
    // repack LDS tile (128 rows x 32 j) -> A-frags ks == jb of write buffer (8 tiles x 64 frag-lanes)
#pragma unroll
    for (int rr = 0; rr < 2; rr++) {
        int fr = threadIdx.x + 256 * rr;       // 0..511
        int mt8 = fr >> 6, fl = fr & 63;
        int qk = fl >> 4, rloc = mt8 * 16 + (fl & 15);
        const float4 v0 = *reinterpret_cast<const float4*>(&hbuf[rloc * 36 + qk * 8]);
        const float4 v1 = *reinterpret_cast<const float4*>(&hbuf[rloc * 36 + qk * 8 + 4]);
        float src[8] = {v0.x, v0.y, v0.z, v0.w, v1.x, v1.y, v1.z, v1.w};
        bf16x8 hv, lv;
#pragma unroll
        for (int s = 0; s < 8; s++) {
            ushortt hi, lo; splitbf(src[s], hi, lo);
            hv[s] = (short)hi; lv[s] = (short)lo;
        }
        unsigned base = ((unsigned)((mb*8 + mt8) * KS + jb) * 64 + fl) * 8;
        *reinterpret_cast<bf16x8*>(WAh + base) = hv;
        *reinterpret_cast<bf16x8*>(WAl + base) = lv;
    }
    // encoder write-ahead: next step's x into write buffer ks=16 (slots 0,1)
    if (ENC && jb == 0 && threadIdx.x < 128) {
        int row = mb * 128 + threadIdx.x;
        int tn = (t < TT - 1) ? (t + 1) : (TT - 1);
        const float* p = xsrc + (((size_t)(row >> 7) * TT + tn) * OO + (row & 127)) * 2;
        ushortt h0, l0, h1, l1;
        splitbf(p[0], h0, l0); splitbf(p[1], h1, l1);
        unsigned xb = ((unsigned)((row >> 4) * KS + 16) * 64 + (row & 15)) * 8;
        WAh[xb + 0] = h0; WAl[xb + 0] = l0;
        WAh[xb + 1] = h1; WAl[xb + 1] = l1;
    }
}

// ================= fused head: t1 = gelu(h@W1^T + b1); d += t1@W2^T; last block finalizes =================
// Block 128 rows x 32 cols; wave 2 mt x 2 nt. Grid 512 (32 mb x 16 nb), mb LOW bits.
#define HEAD_LOADA(Ad, ksv) do { const unsigned ko = (unsigned)(ksv) * 512; \
  _Pragma("unroll") for (int m_ = 0; m_ < 2; m_++) { \
    Ad[m_*2+0] = *reinterpret_cast<const bf16x8*>(Ah + hao[m_] + ko); \
    Ad[m_*2+1] = *reinterpret_cast<const bf16x8*>(Al + hao[m_] + ko); \
  } } while(0)
#define HEAD_LOADB(Bd, ksv) do { const unsigned ko = (unsigned)(ksv) * 512; \
  _Pragma("unroll") for (int n_ = 0; n_ < 2; n_++) { \
    Bd[n_*2+0] = *reinterpret_cast<const bf16x8*>(Bh + hbo[n_] + ko); \
    Bd[n_*2+1] = *reinterpret_cast<const bf16x8*>(Bl + hbo[n_] + ko); \
  } } while(0)
#define HEAD_MFMA(Av, Bv) do { \
  _Pragma("unroll") for (int m_ = 0; m_ < 2; m_++) \
  _Pragma("unroll") for (int n_ = 0; n_ < 2; n_++) { \
    acc[m_][n_] = __builtin_amdgcn_mfma_f32_16x16x32_bf16(Av[m_*2+0], Bv[n_*2+0], acc[m_][n_], 0,0,0); \
    acc[m_][n_] = __builtin_amdgcn_mfma_f32_16x16x32_bf16(Av[m_*2+0], Bv[n_*2+1], acc[m_][n_], 0,0,0); \
    acc[m_][n_] = __builtin_amdgcn_mfma_f32_16x16x32_bf16(Av[m_*2+1], Bv[n_*2+0], acc[m_][n_], 0,0,0); \
  } } while(0)

__global__ __launch_bounds__(256, 2) void head_kernel(
    ushortt* Ah, ushortt* Al,                 // h frags (also x write target)
    const ushortt* __restrict__ Bh, const ushortt* __restrict__ Bl,   // W1_ext frags
    const float* __restrict__ W2, const float* __restrict__ b2,
    float* __restrict__ d, unsigned* __restrict__ ctr,
    float* state, float* __restrict__ out, int t)
{
    const int mb = blockIdx.x & 31;   // LOW bits -> XCD = mb%8 (matches step_kernel)
    const int nb = blockIdx.x >> 5;   // 0..15  (32 cols)
    const int w = threadIdx.x >> 6, lane = threadIdx.x & 63;
    const int quad = lane >> 4, l15 = lane & 15;
    const int mtg = mb * 8 + w * 2;

    f32x4 acc[2][2];
#pragma unroll
    for (int a = 0; a < 2; a++)
#pragma unroll
        for (int b = 0; b < 2; b++) acc[a][b] = (f32x4){0.f,0.f,0.f,0.f};

    unsigned hao[2], hbo[2];
#pragma unroll
    for (int mt = 0; mt < 2; mt++) hao[mt] = (unsigned)(mtg + mt) * (KS*512) + lane * 8;
#pragma unroll
    for (int nt = 0; nt < 2; nt++) hbo[nt] = (unsigned)(nb*2 + nt) * (KS*512) + lane * 8;

    bf16x8 aC[4], bC[4], aN[4], bN[4];
    HEAD_LOADA(aC, 0); HEAD_LOADB(bC, 0);
#pragma unroll 1
    for (int ks = 0; ks < 16; ks += 2) {
        HEAD_LOADA(aN, ks+1); HEAD_LOADB(bN, ks+1);
        HEAD_MFMA(aC, bC);
        HEAD_LOADA(aC, ks+2); HEAD_LOADB(bC, ks+2);
        HEAD_MFMA(aN, bN);
    }
    HEAD_MFMA(aC, bC);

    // ---- GELU + W2 partial reduction ----
    float w2a[2], w2b[2];
#pragma unroll
    for (int nt = 0; nt < 2; nt++) {
        int col = (nb*2 + nt) * 16 + l15;
        w2a[nt] = W2[col]; w2b[nt] = W2[HH + col];
    }
    float p0[2][4], p1[2][4];
#pragma unroll
    for (int mt = 0; mt < 2; mt++)
#pragma unroll
        for (int reg = 0; reg < 4; reg++) { p0[mt][reg] = 0.f; p1[mt][reg] = 0.f; }
#pragma unroll
    for (int mt = 0; mt < 2; mt++)
#pragma unroll
        for (int nt = 0; nt < 2; nt++)
#pragma unroll
            for (int reg = 0; reg < 4; reg++) {
                float v = acc[mt][nt][reg];
                v = 0.5f * v * (1.0f + erff(v * 0.70710678118654752440f));
                p0[mt][reg] = fmaf(v, w2a[nt], p0[mt][reg]);
                p1[mt][reg] = fmaf(v, w2b[nt], p1[mt][reg]);
            }
#pragma unroll
    for (int m = 1; m < 16; m <<= 1)
#pragma unroll
        for (int mt = 0; mt < 2; mt++)
#pragma unroll
            for (int reg = 0; reg < 4; reg++) {
                p0[mt][reg] += __shfl_xor(p0[mt][reg], m, 64);
                p1[mt][reg] += __shfl_xor(p1[mt][reg], m, 64);
            }
    if (l15 == 0) {
#pragma unroll
        for (int mt = 0; mt < 2; mt++)
#pragma unroll
            for (int reg = 0; reg < 4; reg++) {
                int row = (mtg + mt) * 16 + quad * 4 + reg;
                atomicAdd(&d[row * 2], p0[mt][reg]);
                atomicAdd(&d[row * 2 + 1], p1[mt][reg]);
            }
    }

    // ---- last-block finalize ----
    __syncthreads();                    // drains this block's atomics
    __shared__ unsigned lastv;
    if (threadIdx.x == 0) lastv = atomicAdd(ctr, 1u);
    __syncthreads();
    if (lastv == 511) {
        __threadfence();
#pragma unroll 1
        for (int rr = 0; rr < 16; rr++) {
            int row = rr * 256 + threadIdx.x;
            float d0 = d[row * 2]     + b2[0];
            float d1 = d[row * 2 + 1] + b2[1];
            d0 = 2.0f * tanhf(d0 * 0.5f);
            d1 = 2.0f * tanhf(d1 * 0.5f);
            float s0 = state[row * 2] + d0;
            s0 = fminf(fmaxf(s0, -90.f), 90.f);
            float s1 = state[row * 2 + 1] + d1;
            float rrm = fmodf(s1, 360.f);
            if (rrm < 0.f) rrm += 360.f;
            state[row * 2] = s0; state[row * 2 + 1] = rrm;
            float* op = out + (((size_t)(row >> 7) * HOR + t) * OO + (row & 127)) * 2;
            op[0] = s0; op[1] = rrm;
            ushortt h0, l0, h1, l1;
            splitbf(s0, h0, l0); splitbf(rrm, h1, l1);
            unsigned xb = ((unsigned)((row >> 4) * KS + 16) * 64 + (row & 15)) * 8;
            Ah[xb + 0] = h0; Al[xb + 0] = l0;
            Ah[xb + 1] = h1; Al[xb + 1] = l1;
        }
    }
}

// ================= prep: U = Wi*W_emb, cin = Wi*b_emb + bi  (wave per output j) =================
__global__ __launch_bounds__(256) void fuse_kernel(
    const float* __restrict__ Wi_enc, const float* __restrict__ bi_enc,
    const float* __restrict__ Wi_cell, const float* __restrict__ bi_cell,
    const float* __restrict__ W_emb, const float* __restrict__ b_emb,
    float* __restrict__ Ue, float* __restrict__ ce,
    float* __restrict__ Ud, float* __restrict__ cd) {
    int w = threadIdx.x >> 6, lane = threadIdx.x & 63;
    int gidx = blockIdx.x * 4 + w;          // 0..3071
    int which = gidx >= G3;
    int j = gidx - which * G3;
    const float* Wi = which ? Wi_cell : Wi_enc;
    const float* bi = which ? bi_cell : bi_enc;
    float u0 = 0.f, u1 = 0.f, cc = 0.f;
#pragma unroll
    for (int i = 0; i < 8; i++) {
        int k = i * 64 + lane;
        float wv = Wi[(size_t)j * HH + k];
        u0 = fmaf(wv, W_emb[2*k],   u0);
        u1 = fmaf(wv, W_emb[2*k+1], u1);
        cc = fmaf(wv, b_emb[k],     cc);
    }
#pragma unroll
    for (int m = 1; m < 64; m <<= 1) {
        u0 += __shfl_xor(u0, m, 64);
        u1 += __shfl_xor(u1, m, 64);
        cc += __shfl_xor(cc, m, 64);
    }
    if (lane == 0) {
        float* Uo = which ? Ud : Ue;
        float* cv = which ? cd : ce;
        Uo[j * 2 + 0] = u0; Uo[j * 2 + 1] = u1; cv[j] = cc + bi[j];
    }
}

// ================= prep: pack W_ext into split-bf16 B-frags (one thread per k-octet) =================
__global__ void pack_frag(const float* __restrict__ W, const float* __restrict__ bhv,
                          const float* __restrict__ U, const float* __restrict__ cin,
                          const float* __restrict__ b1,
                          ushortt* __restrict__ Fh, ushortt* __restrict__ Fl, int N) {
    int idx = blockIdx.x * 256 + threadIdx.x;
    if (idx >= N * KS * 4) return;
    int n = idx / (KS * 4);
    int rem = idx - n * (KS * 4);
    int ks = rem >> 2, quad = rem & 3;
    int nt = n >> 4, l15 = n & 15;
    ushortt hv[8], lv[8];
#pragma unroll
    for (int s = 0; s < 8; s++) {
        int k = ks * 32 + quad * 8 + s;
        float v = 0.f;
        if (k < 512) v = W[(size_t)n * 512 + k];
        else if (k == 512) v = (U && n < 1024) ? U[n * 2 + 0] : 0.f;
        else if (k == 513) v = (U && n < 1024) ? U[n * 2 + 1] : 0.f;
        else if (k == 514) v = U ? ((n < 1024) ? (cin[n] + bhv[n]) : bhv[n]) : b1[n];
        ushortt hi, lo; splitbf(v, hi, lo);
        hv[s] = hi; lv[s] = lo;
    }
    size_t pos = ((size_t)(nt * KS + ks) * 64 + quad * 16 + l15) * 8;
#pragma unroll
    for (int s = 0; s < 8; s++) { Fh[pos + s] = hv[s]; Fl[pos + s] = lv[s]; }
}

// ================= prep: ctx = z_ctx @ W_ctx^T + b_ctx =================
__global__ void ctx_kernel(const float* __restrict__ z, const float* __restrict__ Wc,
                           const float* __restrict__ bc, float* __restrict__ ctx) {
    int idx = blockIdx.x * 256 + threadIdx.x;
    int b = idx >> 9, j = idx & 511;
    float acc = bc[j];
    const float4* zp = (const float4*)(z + (size_t)b * CTXD);
    const float4* wp = (const float4*)(Wc + (size_t)j * CTXD);
    for (int k = 0; k < CTXD / 4; k++) {
        float4 a = zp[k], ww = wp[k];
        acc = fmaf(a.x, ww.x, fmaf(a.y, ww.y, fmaf(a.z, ww.z, fmaf(a.w, ww.w, acc))));
    }
    ctx[idx] = acc;
}

// ================= init =================
__global__ void init_kernel(const float* __restrict__ traj,
                            ushortt* __restrict__ Ah0, ushortt* __restrict__ Al0,
                            ushortt* __restrict__ Ah1, ushortt* __restrict__ Al1,
                            float* __restrict__ state, float* __restrict__ d,
                            unsigned* __restrict__ ctr) {
    int b = blockIdx.x;
    if (b < 1024) {
        int item = b * 256 + threadIdx.x;
        int mt = item >> 10, ks = (item >> 6) & 15, q4 = item & 63;
        size_t pos32 = ((size_t)(mt * KS + ks)) * 256 + q4 * 4;
        uint4 z = {0u,0u,0u,0u};
        *reinterpret_cast<uint4*>(((unsigned*)Ah0) + pos32) = z;
        *reinterpret_cast<uint4*>(((unsigned*)Al0) + pos32) = z;
    } else if (b < 1040) {
        int row = (b - 1024) * 256 + threadIdx.x;
        int bi = row >> 7, o = row & 127;
        const float* tp = traj + (((size_t)bi * TT + 0) * OO + o) * 2;
        ushortt xh0, xl0, xh1, xl1;
        splitbf(tp[0], xh0, xl0); splitbf(tp[1], xh1, xl1);
        for (int qk = 0; qk < 4; qk++)
            for (int slot = 0; slot < 8; slot++) {
                size_t p = (((size_t)(row >> 4) * KS + 16) * 64 + qk * 16 + (row & 15)) * 8 + slot;
                ushortt vh0 = 0, vl0 = 0, vh1 = 0;
                if (qk == 0 && slot == 0) { vh0 = xh0; vl0 = xl0; }
                else if (qk == 0 && slot == 1) { vh0 = xh1; vl0 = xl1; }
                else if (qk == 0 && slot == 2) { vh0 = 0x3F80; vh1 = 0x3F80; }
                Ah0[p] = vh0; Al0[p] = vl0; Ah1[p] = vh1; Al1[p] = 0;
            }
        const float* sp = traj + (((size_t)bi * TT + 23) * OO + o) * 2;
        state[row * 2] = sp[0]; state[row * 2 + 1] = sp[1];
    } else if (b < 1424) {
        int i = (b - 1040) * 256 + threadIdx.x;
        float4 z = {0.f,0.f,0.f,0.f};
        reinterpret_cast<float4*>(d)[i] = z;
    } else {
        if (threadIdx.x < 48) ctr[threadIdx.x] = 0u;
    }
}

extern "C" void kernel_launch(void* const* d_in, const int* in_sizes, int n_in,
                              void* d_out, int out_size, void* d_ws, size_t ws_size,
                              hipStream_t stream) {
    const float* z_ctx   = (const float*)d_in[0];
    const float* traj    = (const float*)d_in[1];
    const float* W_emb   = (const float*)d_in[2];
    const float* b_emb   = (const float*)d_in[3];
    const float* W_ctx   = (const float*)d_in[4];
    const float* b_ctx   = (const float*)d_in[5];
    const float* Wi_enc  = (const float*)d_in[6];
    const float* Wh_enc  = (const float*)d_in[7];
    const float* bi_enc  = (const float*)d_in[8];
    const float* bh_enc  = (const float*)d_in[9];
    const float* Wi_cell = (const float*)d_in[10];
    const float* Wh_cell = (const float*)d_in[11];
    const float* bi_cell = (const float*)d_in[12];
    const float* bh_cell = (const float*)d_in[13];
    const float* W1      = (const float*)d_in[14];
    const float* b1      = (const float*)d_in[15];
    const float* W2      = (const float*)d_in[16];
    const float* b2      = (const float*)d_in[17];
    float* out = (float*)d_out;

    char* ws = (char*)d_ws;
    size_t off = 0;
    auto alloc = [&](size_t bytes) { void* p = ws + off; off += (bytes + 255) & ~(size_t)255; return p; };
    const size_t hfrag = (size_t)256 * KS * 512 * 2;
    const size_t wfrag = (size_t)96  * KS * 512 * 2;
    const size_t w1frag = (size_t)32 * KS * 512 * 2;
    ushortt* Ah0 = (ushortt*)alloc(hfrag);
    ushortt* Al0 = (ushortt*)alloc(hfrag);
    ushortt* Ah1 = (ushortt*)alloc(hfrag);
    ushortt* Al1 = (ushortt*)alloc(hfrag);
    ushortt* WheH = (ushortt*)alloc(wfrag);
    ushortt* WheL = (ushortt*)alloc(wfrag);
    ushortt* WhdH = (ushortt*)alloc(wfrag);
    ushortt* WhdL = (ushortt*)alloc(wfrag);
    ushortt* W1H  = (ushortt*)alloc(w1frag);
    ushortt* W1L  = (ushortt*)alloc(w1frag);
    float*   state = (float*)alloc((size_t)NN * 2 * 4);
    float*   ctxb  = (float*)alloc((size_t)BB * HH * 4);
    float*   Ue    = (float*)alloc((size_t)G3 * 2 * 4);
    float*   ce    = (float*)alloc((size_t)G3 * 4);
    float*   Ud    = (float*)alloc((size_t)G3 * 2 * 4);
    float*   cd    = (float*)alloc((size_t)G3 * 4);
    float*   dbuf  = (float*)alloc((size_t)HOR * NN * 2 * 4);
    unsigned* ctr  = (unsigned*)alloc(HOR * 4);

    ushortt* bufAh[2] = {Ah0, Ah1};
    ushortt* bufAl[2] = {Al0, Al1};

    fuse_kernel<<<768, 256, 0, stream>>>(Wi_enc, bi_enc, Wi_cell, bi_cell,
                                         W_emb, b_emb, Ue, ce, Ud, cd);
    ctx_kernel<<<(BB * HH) / 256, 256, 0, stream>>>(z_ctx, W_ctx, b_ctx, ctxb);
    pack_frag<<<(G3 * KS * 4 + 255) / 256, 256, 0, stream>>>(Wh_enc, bh_enc, Ue, ce, nullptr, WheH, WheL, G3);
    pack_frag<<<(G3 * KS * 4 + 255) / 256, 256, 0, stream>>>(Wh_cell, bh_cell, Ud, cd, nullptr, WhdH, WhdL, G3);
    pack_frag<<<(HH * KS * 4 + 255) / 256, 256, 0, stream>>>(W1, nullptr, nullptr, nullptr, b1, W1H, W1L, HH);
    init_kernel<<<1425, 256, 0, stream>>>(traj, Ah0, Al0, Ah1, Al1, state, dbuf, ctr);

    // ---- encoder: 24 fused steps ----
    for (int t = 0; t < TT; t++) {
        int rp = t & 1, wp = (t + 1) & 1;
        step_kernel<true><<<512, 256, 0, stream>>>(bufAh[rp], bufAl[rp], bufAh[wp], bufAl[wp],
                                                   WheH, WheL, Ue, ce, traj, t, ctxb);
    }
    // ---- decoder: 48 steps x (step + head) ----
    for (int t = 0; t < HOR; t++) {
        int s = TT + t;
        int rp = s & 1, wp = (s + 1) & 1;
        step_kernel<false><<<512, 256, 0, stream>>>(bufAh[rp], bufAl[rp], bufAh[wp], bufAl[wp],
                                                    WhdH, WhdL, Ud, cd, state, t, nullptr);
        head_kernel<<<512, 256, 0, stream>>>(bufAh[wp], bufAl[wp], W1H, W1L, W2, b2,
                                             dbuf + (size_t)t * NN * 2, ctr + t, state, out, t);
    }
}